// Round 1
// baseline (1261.052 us; speedup 1.0000x reference)
//
#include <hip/hip_runtime.h>

#define HW    4096
#define CIN   256
#define COUT  256
#define NB    4

// ws layout (floats):
// off_buf [16384][18]      @ 0            (294912)
// wt      [2304][256]      @ 294912       (589824)
// outpre  [4][256][4096]   @ 884736       (4194304)
// bn      [512]            @ 5079040
#define WS_WT   294912
#define WS_PRE  884736
#define WS_BN   5079040

__global__ __launch_bounds__(256) void k_transpose(const float* __restrict__ w_conv,
                                                   float* __restrict__ wt) {
    int t = blockIdx.x * 256 + threadIdx.x;      // t < 2304*256
    int o = t & 255;
    int ck = t >> 8;                             // c*9+k
    wt[ck * 256 + o] = w_conv[o * 2304 + ck];
}

__global__ __launch_bounds__(256) void k_offconv(const float* __restrict__ x,
                                                 const float* __restrict__ w_off,
                                                 const float* __restrict__ b_off,
                                                 float* __restrict__ off_buf) {
    __shared__ float rows[2][3][66];
    int bh = blockIdx.x;               // b*64 + h
    int b = bh >> 6, h = bh & 63;
    int tid = threadIdx.x;
    int w = tid & 63, cg = tid >> 6;   // wave id = cg

    if (tid < 12) {                    // zero halo cols (never rewritten)
        int bufi = tid / 6, r = (tid % 6) >> 1, side = tid & 1;
        rows[bufi][r][side * 65] = 0.f;
    }
    float acc[5] = {0.f, 0.f, 0.f, 0.f, 0.f};
    const float* xb = x + b * (CIN * HW);

    // stage c=0 into buf 0
    if (tid < 192) {
        int r = tid >> 6, wl = tid & 63;
        int y = h + r - 1;
        rows[0][r][wl + 1] = (y >= 0 && y < 64) ? xb[y * 64 + wl] : 0.f;
    }
    __syncthreads();

    for (int c = 0; c < CIN; ++c) {
        int cur = c & 1;
        if (c + 1 < CIN && tid < 192) {            // prefetch next plane rows
            int r = tid >> 6, wl = tid & 63;
            int y = h + r - 1;
            rows[cur ^ 1][r][wl + 1] = (y >= 0 && y < 64) ? xb[(c + 1) * HW + y * 64 + wl] : 0.f;
        }
        float v[9];
#pragma unroll
        for (int dy = 0; dy < 3; ++dy)
#pragma unroll
            for (int dx = 0; dx < 3; ++dx)
                v[dy * 3 + dx] = rows[cur][dy][w + dx];
#pragma unroll
        for (int m = 0; m < 5; ++m) {
            int ch = cg + 4 * m;
            if (ch < 18) {
                const float* wp = w_off + __builtin_amdgcn_readfirstlane(ch * (CIN * 9) + c * 9);
#pragma unroll
                for (int tq = 0; tq < 9; ++tq) acc[m] += wp[tq] * v[tq];
            }
        }
        __syncthreads();
    }
    int pix = bh * 64 + w;   // = b*4096 + h*64 + w
#pragma unroll
    for (int m = 0; m < 5; ++m) {
        int ch = cg + 4 * m;
        if (ch < 18) off_buf[pix * 18 + ch] = acc[m] + b_off[ch];
    }
}

__global__ __launch_bounds__(256) void k_main(const float* __restrict__ x,
                                              const float* __restrict__ off_buf,
                                              const float* __restrict__ wt,
                                              float* __restrict__ outpre) {
    __shared__ float s_lds[144 * 64];
    int blk = blockIdx.x;      // 0..255 : one image row (b,h)
    int b = blk >> 6;
    int h = blk & 63;
    int tid = threadIdx.x;
    int l = tid & 63;          // lane = pixel column
    int wv = tid >> 6;         // wave = o-group

    // ---- per-pixel sampling metadata for all 9 taps (compile-time indexed) ----
    int pix = blk * 64 + l;
    int cy0[9], cy1[9], cx0[9], cx1[9];
    float wy0m[9], wy1m[9], wx0m[9], wx1m[9];
#pragma unroll
    for (int k = 0; k < 9; ++k) {
        float offy = off_buf[pix * 18 + 2 * k];
        float offx = off_buf[pix * 18 + 2 * k + 1];
        float py = (float)h + (float)(k / 3 - 1) + offy;
        float px = (float)l + (float)(k % 3 - 1) + offx;
        float fy0 = floorf(py), fx0 = floorf(px);
        int y0 = (int)fy0, x0 = (int)fx0;
        float fy = py - fy0, fx = px - fx0;
        float vy0 = (y0 >= 0 && y0 < 64) ? 1.f : 0.f;
        float vy1 = (y0 >= -1 && y0 < 63) ? 1.f : 0.f;
        float vx0 = (x0 >= 0 && x0 < 64) ? 1.f : 0.f;
        float vx1 = (x0 >= -1 && x0 < 63) ? 1.f : 0.f;
        wy0m[k] = (1.f - fy) * vy0;
        wy1m[k] = fy * vy1;
        wx0m[k] = (1.f - fx) * vx0;
        wx1m[k] = fx * vx1;
        cy0[k] = min(max(y0, 0), 63) * 64;
        cy1[k] = min(max(y0 + 1, 0), 63) * 64;
        cx0[k] = min(max(x0, 0), 63);
        cx1[k] = min(max(x0 + 1, 0), 63);
    }

    float acc[64];
#pragma unroll
    for (int j = 0; j < 64; ++j) acc[j] = 0.f;

    const float* xb = x + b * (CIN * HW);
    int rest0 = wv;

    for (int ct = 0; ct < 16; ++ct) {
        __syncthreads();   // s_lds reuse guard
        // ---- gather phase: 16 channels x 9 taps x 64 pixels ----
#pragma unroll
        for (int k = 0; k < 9; ++k) {
#pragma unroll
            for (int u = 0; u < 4; ++u) {
                int i = k * 4 + u;
                int rest = rest0 + 4 * i;      // kk_local in [0,144)
                int cl = rest & 15;
                const float* pl = xb + (ct * 16 + cl) * HW;
                float p00 = pl[cy0[k] + cx0[k]];
                float p01 = pl[cy0[k] + cx1[k]];
                float p10 = pl[cy1[k] + cx0[k]];
                float p11 = pl[cy1[k] + cx1[k]];
                float v = wy0m[k] * (wx0m[k] * p00 + wx1m[k] * p01) +
                          wy1m[k] * (wx0m[k] * p10 + wx1m[k] * p11);
                s_lds[rest * 64 + l] = v;      // coalesced: flat = tid + 256*i
            }
        }
        __syncthreads();
        // ---- FMA phase: out[p][o] += s[p][kk] * wt[kk][o] ----
#pragma unroll 2
        for (int kkl = 0; kkl < 144; ++kkl) {
            int k = kkl >> 4, cl = kkl & 15;
            int kkg = (ct * 16 + cl) * 9 + k;
            float sv = s_lds[kkl * 64 + l];
            const float* wp = wt + __builtin_amdgcn_readfirstlane(kkg * 256 + wv * 64);
#pragma unroll
            for (int j = 0; j < 64; ++j) acc[j] = fmaf(wp[j], sv, acc[j]);
        }
    }
    float* op = outpre + (b * COUT) * HW + h * 64 + l;
#pragma unroll
    for (int j = 0; j < 64; ++j) op[(wv * 64 + j) * HW] = acc[j];
}

__global__ __launch_bounds__(256) void k_stats(const float* __restrict__ outpre,
                                               const float* __restrict__ gamma,
                                               const float* __restrict__ beta,
                                               float* __restrict__ bn) {
    int o = blockIdx.x;
    int tid = threadIdx.x;
    float s = 0.f, sq = 0.f;
    for (int f = tid; f < 16384; f += 256) {
        int bb = f >> 12, hw = f & 4095;
        float v = outpre[((bb * 256 + o) << 12) + hw];
        s += v;
        sq += v * v;
    }
    __shared__ float rs[256], rq[256];
    rs[tid] = s; rq[tid] = sq;
    __syncthreads();
    for (int st = 128; st > 0; st >>= 1) {
        if (tid < st) { rs[tid] += rs[tid + st]; rq[tid] += rq[tid + st]; }
        __syncthreads();
    }
    if (tid == 0) {
        float mu = rs[0] * (1.f / 16384.f);
        float var = rq[0] * (1.f / 16384.f) - mu * mu;
        float sc = gamma[o] / sqrtf(var + 1e-5f);
        bn[o] = sc;
        bn[256 + o] = beta[o] - mu * sc;
    }
}

__global__ __launch_bounds__(256) void k_apply(const float* __restrict__ outpre,
                                               const float* __restrict__ bn,
                                               float* __restrict__ out) {
    int i4 = blockIdx.x * 256 + threadIdx.x;   // 1048576 float4s
    int o = (i4 >> 10) & 255;
    float sc = bn[o], sh = bn[256 + o];
    float4 v = ((const float4*)outpre)[i4];
    v.x = fmaxf(fmaf(v.x, sc, sh), 0.f);
    v.y = fmaxf(fmaf(v.y, sc, sh), 0.f);
    v.z = fmaxf(fmaf(v.z, sc, sh), 0.f);
    v.w = fmaxf(fmaf(v.w, sc, sh), 0.f);
    ((float4*)out)[i4] = v;
}

extern "C" void kernel_launch(void* const* d_in, const int* in_sizes, int n_in,
                              void* d_out, int out_size, void* d_ws, size_t ws_size,
                              hipStream_t stream) {
    const float* x      = (const float*)d_in[0];
    const float* w_off  = (const float*)d_in[1];
    const float* b_off  = (const float*)d_in[2];
    const float* w_conv = (const float*)d_in[3];
    const float* gamma  = (const float*)d_in[4];
    const float* beta   = (const float*)d_in[5];
    float* ws = (float*)d_ws;
    float* off_buf = ws;
    float* wt      = ws + WS_WT;
    float* outpre  = ws + WS_PRE;
    float* bn      = ws + WS_BN;
    float* out = (float*)d_out;

    hipLaunchKernelGGL(k_transpose, dim3(2304), dim3(256), 0, stream, w_conv, wt);
    hipLaunchKernelGGL(k_offconv,   dim3(256),  dim3(256), 0, stream, x, w_off, b_off, off_buf);
    hipLaunchKernelGGL(k_main,      dim3(256),  dim3(256), 0, stream, x, off_buf, wt, outpre);
    hipLaunchKernelGGL(k_stats,     dim3(256),  dim3(256), 0, stream, outpre, gamma, beta, bn);
    hipLaunchKernelGGL(k_apply,     dim3(4096), dim3(256), 0, stream, outpre, bn, out);
}

// Round 3
// 925.589 us; speedup vs baseline: 1.3624x; 1.3624x over previous
//
#include <hip/hip_runtime.h>

#define HW    4096
#define CIN   256
#define COUT  256
#define NB    4

// ws layout (floats):
// off_buf [16384][18]      @ 0            (294912)
// wt      [2304][256]      @ 294912       (589824)
// outpre  [4][256][4096]   @ 884736       (4194304)
// bn      [512]            @ 5079040
#define WS_WT   294912
#define WS_PRE  884736
#define WS_BN   5079040

__global__ __launch_bounds__(256) void k_transpose(const float* __restrict__ w_conv,
                                                   float* __restrict__ wt) {
    int t = blockIdx.x * 256 + threadIdx.x;      // t < 2304*256
    int o = t & 255;
    int ck = t >> 8;                             // c*9+k
    wt[ck * 256 + o] = w_conv[o * 2304 + ck];
}

__global__ __launch_bounds__(256) void k_zero(float* __restrict__ outpre) {
    int i4 = blockIdx.x * 256 + threadIdx.x;     // 4194304/4 float4s
    ((float4*)outpre)[i4] = make_float4(0.f, 0.f, 0.f, 0.f);
}

__global__ __launch_bounds__(256) void k_offinit(const float* __restrict__ b_off,
                                                 float* __restrict__ off_buf) {
    int i = blockIdx.x * 256 + threadIdx.x;      // < 294912
    off_buf[i] = b_off[i % 18];
}

// 4-way channel split: blk = row*4 + s, channels [s*64, s*64+64)
__global__ __launch_bounds__(256) void k_offconv(const float* __restrict__ x,
                                                 const float* __restrict__ w_off,
                                                 float* __restrict__ off_buf) {
    __shared__ float rows[2][3][66];
    int blk = blockIdx.x;
    int bh = blk >> 2;                 // b*64 + h
    int s  = blk & 3;
    int c0 = s * 64;
    int b = bh >> 6, h = bh & 63;
    int tid = threadIdx.x;
    int w = tid & 63, cg = tid >> 6;   // wave id = cg

    if (tid < 12) {                    // zero halo cols (never rewritten)
        int bufi = tid / 6, r = (tid % 6) >> 1, side = tid & 1;
        rows[bufi][r][side * 65] = 0.f;
    }
    float acc[5] = {0.f, 0.f, 0.f, 0.f, 0.f};
    const float* xb = x + b * (CIN * HW);

    // stage c=c0 into buf 0
    if (tid < 192) {
        int r = tid >> 6, wl = tid & 63;
        int y = h + r - 1;
        rows[0][r][wl + 1] = (y >= 0 && y < 64) ? xb[c0 * HW + y * 64 + wl] : 0.f;
    }
    __syncthreads();

    for (int ci = 0; ci < 64; ++ci) {
        int c = c0 + ci;
        int cur = ci & 1;
        if (ci + 1 < 64 && tid < 192) {            // prefetch next plane rows
            int r = tid >> 6, wl = tid & 63;
            int y = h + r - 1;
            rows[cur ^ 1][r][wl + 1] = (y >= 0 && y < 64) ? xb[(c + 1) * HW + y * 64 + wl] : 0.f;
        }
        float v[9];
#pragma unroll
        for (int dy = 0; dy < 3; ++dy)
#pragma unroll
            for (int dx = 0; dx < 3; ++dx)
                v[dy * 3 + dx] = rows[cur][dy][w + dx];
#pragma unroll
        for (int m = 0; m < 5; ++m) {
            int ch = cg + 4 * m;
            if (ch < 18) {
                const float* wp = w_off + __builtin_amdgcn_readfirstlane(ch * (CIN * 9) + c * 9);
#pragma unroll
                for (int tq = 0; tq < 9; ++tq) acc[m] += wp[tq] * v[tq];
            }
        }
        __syncthreads();
    }
    int pix = bh * 64 + w;   // = b*4096 + h*64 + w
#pragma unroll
    for (int m = 0; m < 5; ++m) {
        int ch = cg + 4 * m;
        if (ch < 18) unsafeAtomicAdd(&off_buf[pix * 18 + ch], acc[m]);
    }
}

// 4-way K split: blk = row*4 + s, c-tiles [s*4, s*4+4)
__global__ __launch_bounds__(256, 4) void k_main(const float* __restrict__ x,
                                                 const float* __restrict__ off_buf,
                                                 const float* __restrict__ wt,
                                                 float* __restrict__ outpre) {
    __shared__ float s_lds[144 * 64];
    int blk = blockIdx.x;
    int row = blk >> 2;        // 0..255 : one image row (b,h)
    int s   = blk & 3;
    int b = row >> 6;
    int h = row & 63;
    int tid = threadIdx.x;
    int l = tid & 63;          // lane = pixel column
    int wv = tid >> 6;         // wave = o-group

    // ---- per-pixel sampling metadata for all 9 taps (compile-time indexed) ----
    int pix = row * 64 + l;
    int cy0[9], cy1[9], cx0[9], cx1[9];
    float wy0m[9], wy1m[9], wx0m[9], wx1m[9];
#pragma unroll
    for (int k = 0; k < 9; ++k) {
        float offy = off_buf[pix * 18 + 2 * k];
        float offx = off_buf[pix * 18 + 2 * k + 1];
        float py = (float)h + (float)(k / 3 - 1) + offy;
        float px = (float)l + (float)(k % 3 - 1) + offx;
        float fy0 = floorf(py), fx0 = floorf(px);
        int y0 = (int)fy0, x0 = (int)fx0;
        float fy = py - fy0, fx = px - fx0;
        float vy0 = (y0 >= 0 && y0 < 64) ? 1.f : 0.f;
        float vy1 = (y0 >= -1 && y0 < 63) ? 1.f : 0.f;
        float vx0 = (x0 >= 0 && x0 < 64) ? 1.f : 0.f;
        float vx1 = (x0 >= -1 && x0 < 63) ? 1.f : 0.f;
        wy0m[k] = (1.f - fy) * vy0;
        wy1m[k] = fy * vy1;
        wx0m[k] = (1.f - fx) * vx0;
        wx1m[k] = fx * vx1;
        cy0[k] = min(max(y0, 0), 63) * 64;
        cy1[k] = min(max(y0 + 1, 0), 63) * 64;
        cx0[k] = min(max(x0, 0), 63);
        cx1[k] = min(max(x0 + 1, 0), 63);
    }

    float acc[64];
#pragma unroll
    for (int j = 0; j < 64; ++j) acc[j] = 0.f;

    const float* xb = x + b * (CIN * HW);
    int rest0 = wv;

    for (int ct4 = 0; ct4 < 4; ++ct4) {
        int ct = s * 4 + ct4;
        __syncthreads();   // s_lds reuse guard
        // ---- gather phase: 16 channels x 9 taps x 64 pixels ----
#pragma unroll
        for (int k = 0; k < 9; ++k) {
#pragma unroll
            for (int u = 0; u < 4; ++u) {
                int i = k * 4 + u;
                int rest = rest0 + 4 * i;      // kk_local in [0,144)
                int cl = rest & 15;
                const float* pl = xb + (ct * 16 + cl) * HW;
                float p00 = pl[cy0[k] + cx0[k]];
                float p01 = pl[cy0[k] + cx1[k]];
                float p10 = pl[cy1[k] + cx0[k]];
                float p11 = pl[cy1[k] + cx1[k]];
                float v = wy0m[k] * (wx0m[k] * p00 + wx1m[k] * p01) +
                          wy1m[k] * (wx0m[k] * p10 + wx1m[k] * p11);
                s_lds[rest * 64 + l] = v;      // coalesced: flat = tid + 256*i
            }
        }
        __syncthreads();
        // ---- FMA phase: out[p][o] += s[p][kk] * wt[kk][o] ----
#pragma unroll 2
        for (int kkl = 0; kkl < 144; ++kkl) {
            int k = kkl >> 4, cl = kkl & 15;
            int kkg = (ct * 16 + cl) * 9 + k;
            float sv = s_lds[kkl * 64 + l];
            const float* wp = wt + __builtin_amdgcn_readfirstlane(kkg * 256 + wv * 64);
#pragma unroll
            for (int j = 0; j < 64; ++j) acc[j] = fmaf(wp[j], sv, acc[j]);
        }
    }
    float* op = outpre + (b * COUT) * HW + h * 64 + l;
#pragma unroll
    for (int j = 0; j < 64; ++j) unsafeAtomicAdd(&op[(wv * 64 + j) * HW], acc[j]);
}

__global__ __launch_bounds__(1024) void k_stats(const float* __restrict__ outpre,
                                                const float* __restrict__ gamma,
                                                const float* __restrict__ beta,
                                                float* __restrict__ bn) {
    int o = blockIdx.x;
    int tid = threadIdx.x;
    float s = 0.f, sq = 0.f;
    for (int f = tid; f < 16384; f += 1024) {
        int bb = f >> 12, hw = f & 4095;
        float v = outpre[((bb * 256 + o) << 12) + hw];
        s += v;
        sq += v * v;
    }
    __shared__ float rs[1024], rq[1024];
    rs[tid] = s; rq[tid] = sq;
    __syncthreads();
    for (int st = 512; st > 0; st >>= 1) {
        if (tid < st) { rs[tid] += rs[tid + st]; rq[tid] += rq[tid + st]; }
        __syncthreads();
    }
    if (tid == 0) {
        float mu = rs[0] * (1.f / 16384.f);
        float var = rq[0] * (1.f / 16384.f) - mu * mu;
        float sc = gamma[o] / sqrtf(var + 1e-5f);
        bn[o] = sc;
        bn[256 + o] = beta[o] - mu * sc;
    }
}

__global__ __launch_bounds__(256) void k_apply(const float* __restrict__ outpre,
                                               const float* __restrict__ bn,
                                               float* __restrict__ out) {
    int i4 = blockIdx.x * 256 + threadIdx.x;   // 1048576 float4s
    int o = (i4 >> 10) & 255;
    float sc = bn[o], sh = bn[256 + o];
    float4 v = ((const float4*)outpre)[i4];
    v.x = fmaxf(fmaf(v.x, sc, sh), 0.f);
    v.y = fmaxf(fmaf(v.y, sc, sh), 0.f);
    v.z = fmaxf(fmaf(v.z, sc, sh), 0.f);
    v.w = fmaxf(fmaf(v.w, sc, sh), 0.f);
    ((float4*)out)[i4] = v;
}

extern "C" void kernel_launch(void* const* d_in, const int* in_sizes, int n_in,
                              void* d_out, int out_size, void* d_ws, size_t ws_size,
                              hipStream_t stream) {
    const float* x      = (const float*)d_in[0];
    const float* w_off  = (const float*)d_in[1];
    const float* b_off  = (const float*)d_in[2];
    const float* w_conv = (const float*)d_in[3];
    const float* gamma  = (const float*)d_in[4];
    const float* beta   = (const float*)d_in[5];
    float* ws = (float*)d_ws;
    float* off_buf = ws;
    float* wt      = ws + WS_WT;
    float* outpre  = ws + WS_PRE;
    float* bn      = ws + WS_BN;
    float* out = (float*)d_out;

    hipLaunchKernelGGL(k_transpose, dim3(2304), dim3(256), 0, stream, w_conv, wt);
    hipLaunchKernelGGL(k_zero,      dim3(4096), dim3(256), 0, stream, outpre);
    hipLaunchKernelGGL(k_offinit,   dim3(1152), dim3(256), 0, stream, b_off, off_buf);
    hipLaunchKernelGGL(k_offconv,   dim3(1024), dim3(256), 0, stream, x, w_off, off_buf);
    hipLaunchKernelGGL(k_main,      dim3(1024), dim3(256), 0, stream, x, off_buf, wt, outpre);
    hipLaunchKernelGGL(k_stats,     dim3(256),  dim3(1024), 0, stream, outpre, gamma, beta, bn);
    hipLaunchKernelGGL(k_apply,     dim3(4096), dim3(256), 0, stream, outpre, bn, out);
}

// Round 5
// 558.666 us; speedup vs baseline: 2.2573x; 1.6568x over previous
//
#include <hip/hip_runtime.h>
#include <hip/hip_bf16.h>

#define HW    4096
#define CIN   256
#define COUT  256

// ws layout (floats):
// off_buf [16384][18]      @ 0            (294912)
// wtb     bf16[2304][256]  @ 294912       (294912 floats = 589824 bf16)
// outpre  [4][256][4096]   @ 884736       (4194304)
// bn      [512]            @ 5079040
#define WS_WT   294912
#define WS_PRE  884736
#define WS_BN   5079040

typedef __attribute__((ext_vector_type(8))) short bf16x8;
typedef __attribute__((ext_vector_type(4))) float f32x4;

__device__ inline ushort f2b(float v) {
    __hip_bfloat16 h = __float2bfloat16(v);
    return *reinterpret_cast<ushort*>(&h);
}

// pack w_conv[o][c][tap] (f32) -> wtb[k>>3][o][k&7] (bf16), k = c*9+tap
__global__ __launch_bounds__(256) void k_wtb(const float* __restrict__ wc,
                                             ushort* __restrict__ wtb) {
    int n = blockIdx.x;                       // out channel
#pragma unroll
    for (int i = 0; i < 9; ++i) {
        int k = i * 256 + threadIdx.x;        // 0..2303
        float v = wc[n * 2304 + k];
        wtb[(k >> 3) * 2048 + n * 8 + (k & 7)] = f2b(v);
    }
}

__global__ __launch_bounds__(256) void k_zero(float* __restrict__ outpre) {
    int i4 = blockIdx.x * 256 + threadIdx.x;     // 4194304/4 float4s
    ((float4*)outpre)[i4] = make_float4(0.f, 0.f, 0.f, 0.f);
}

__global__ __launch_bounds__(256) void k_offinit(const float* __restrict__ b_off,
                                                 float* __restrict__ off_buf) {
    int i = blockIdx.x * 256 + threadIdx.x;      // < 294912
    off_buf[i] = b_off[i % 18];
}

// 4-way channel split: blk = row*4 + s, channels [s*64, s*64+64)
__global__ __launch_bounds__(256) void k_offconv(const float* __restrict__ x,
                                                 const float* __restrict__ w_off,
                                                 float* __restrict__ off_buf) {
    __shared__ float rows[2][3][66];
    int blk = blockIdx.x;
    int bh = blk >> 2;                 // b*64 + h
    int s  = blk & 3;
    int c0 = s * 64;
    int b = bh >> 6, h = bh & 63;
    int tid = threadIdx.x;
    int w = tid & 63, cg = tid >> 6;   // wave id = cg

    if (tid < 12) {
        int bufi = tid / 6, r = (tid % 6) >> 1, side = tid & 1;
        rows[bufi][r][side * 65] = 0.f;
    }
    float acc[5] = {0.f, 0.f, 0.f, 0.f, 0.f};
    const float* xb = x + b * (CIN * HW);

    if (tid < 192) {
        int r = tid >> 6, wl = tid & 63;
        int y = h + r - 1;
        rows[0][r][wl + 1] = (y >= 0 && y < 64) ? xb[c0 * HW + y * 64 + wl] : 0.f;
    }
    __syncthreads();

    for (int ci = 0; ci < 64; ++ci) {
        int c = c0 + ci;
        int cur = ci & 1;
        if (ci + 1 < 64 && tid < 192) {
            int r = tid >> 6, wl = tid & 63;
            int y = h + r - 1;
            rows[cur ^ 1][r][wl + 1] = (y >= 0 && y < 64) ? xb[(c + 1) * HW + y * 64 + wl] : 0.f;
        }
        float v[9];
#pragma unroll
        for (int dy = 0; dy < 3; ++dy)
#pragma unroll
            for (int dx = 0; dx < 3; ++dx)
                v[dy * 3 + dx] = rows[cur][dy][w + dx];
#pragma unroll
        for (int m = 0; m < 5; ++m) {
            int ch = cg + 4 * m;
            if (ch < 18) {
                const float* wp = w_off + __builtin_amdgcn_readfirstlane(ch * (CIN * 9) + c * 9);
#pragma unroll
                for (int tq = 0; tq < 9; ++tq) acc[m] += wp[tq] * v[tq];
            }
        }
        __syncthreads();
    }
    int pix = bh * 64 + w;
#pragma unroll
    for (int m = 0; m < 5; ++m) {
        int ch = cg + 4 * m;
        if (ch < 18) unsafeAtomicAdd(&off_buf[pix * 18 + ch], acc[m]);
    }
}

#define PAD_K 296   // 288 + 8 bf16 pad (keeps 16B row alignment, breaks pow2 bank stride)

// grid 2048: blk = mt*4 + s; mt = b*128 + h*2 + half (32-pixel M-tile); s = ksplit (64 ch)
__global__ __launch_bounds__(256, 4) void k_main(const float* __restrict__ x,
                                                 const float* __restrict__ off_buf,
                                                 const ushort* __restrict__ wtb,
                                                 float* __restrict__ outpre) {
    __shared__ ushort A_lds[32 * PAD_K];
    int blk = blockIdx.x;
    int mt  = blk >> 2;
    int s   = blk & 3;
    int b    = mt >> 7;
    int h    = (mt >> 1) & 63;
    int half = mt & 1;
    int tid = threadIdx.x;
    int l  = tid & 63;
    int wv = tid >> 6;                 // wave -> n0 = wv*64
    int px = tid & 31;                 // gather pixel within tile
    int grp = tid >> 5;                // 8 groups x 4 channels

    const float* xb = x + b * (CIN * HW);
    int imgcol = half * 32 + px;
    int pixg = (b * 64 + h) * 64 + imgcol;

    f32x4 acc[2][4];
#pragma unroll
    for (int mi = 0; mi < 2; ++mi)
#pragma unroll
        for (int ni = 0; ni < 4; ++ni)
            acc[mi][ni] = (f32x4){0.f, 0.f, 0.f, 0.f};

    for (int sub = 0; sub < 2; ++sub) {
        int c0 = s * 64 + sub * 32;    // absolute channel base of this A-tile
        __syncthreads();               // protect A_lds reuse
        // ---- gather phase: 32 px x 32 ch x 9 taps -> bf16 LDS ----
        for (int tap = 0; tap < 9; ++tap) {
            float offy = off_buf[pixg * 18 + 2 * tap];
            float offx = off_buf[pixg * 18 + 2 * tap + 1];
            float py  = (float)(h + tap / 3 - 1) + offy;
            float pxf = (float)(imgcol + tap % 3 - 1) + offx;
            float fy0 = floorf(py), fx0 = floorf(pxf);
            int y0 = (int)fy0, x0 = (int)fx0;
            float fy = py - fy0, fx = pxf - fx0;
            float wy0 = (1.f - fy) * ((y0 >= 0 && y0 < 64) ? 1.f : 0.f);
            float wy1 = fy         * ((y0 >= -1 && y0 < 63) ? 1.f : 0.f);
            float wx0 = (1.f - fx) * ((x0 >= 0 && x0 < 64) ? 1.f : 0.f);
            float wx1 = fx         * ((x0 >= -1 && x0 < 63) ? 1.f : 0.f);
            int iy0 = min(max(y0, 0), 63) * 64;
            int iy1 = min(max(y0 + 1, 0), 63) * 64;
            int ix0 = min(max(x0, 0), 63);
            int ix1 = min(max(x0 + 1, 0), 63);
            float w00 = wy0 * wx0, w01 = wy0 * wx1, w10 = wy1 * wx0, w11 = wy1 * wx1;
#pragma unroll
            for (int cl = 0; cl < 4; ++cl) {
                int cloc = grp * 4 + cl;       // 0..31 local channel
                const float* pl = xb + (c0 + cloc) * HW;
                float v = w00 * pl[iy0 + ix0] + w01 * pl[iy0 + ix1] +
                          w10 * pl[iy1 + ix0] + w11 * pl[iy1 + ix1];
                A_lds[px * PAD_K + cloc * 9 + tap] = f2b(v);
            }
        }
        __syncthreads();
        // ---- MFMA phase: K-sub = 288 = 9 steps of 32 ----
        int kg0 = c0 * 9;                       // global k base (multiple of 8)
        for (int st = 0; st < 9; ++st) {
            int kb = st * 32;
            int koff = kb + (l >> 4) * 8;       // k-octet for this lane group
            bf16x8 a0 = *(const bf16x8*)&A_lds[((l & 15)) * PAD_K + koff];
            bf16x8 a1 = *(const bf16x8*)&A_lds[((l & 15) + 16) * PAD_K + koff];
            int ko = ((kg0 + kb) >> 3) + (l >> 4);
            const ushort* bp = wtb + ko * 2048 + (wv * 64 + (l & 15)) * 8;
            bf16x8 b0 = *(const bf16x8*)(bp);
            bf16x8 b1 = *(const bf16x8*)(bp + 128);
            bf16x8 b2 = *(const bf16x8*)(bp + 256);
            bf16x8 b3 = *(const bf16x8*)(bp + 384);
            acc[0][0] = __builtin_amdgcn_mfma_f32_16x16x32_bf16(a0, b0, acc[0][0], 0, 0, 0);
            acc[0][1] = __builtin_amdgcn_mfma_f32_16x16x32_bf16(a0, b1, acc[0][1], 0, 0, 0);
            acc[0][2] = __builtin_amdgcn_mfma_f32_16x16x32_bf16(a0, b2, acc[0][2], 0, 0, 0);
            acc[0][3] = __builtin_amdgcn_mfma_f32_16x16x32_bf16(a0, b3, acc[0][3], 0, 0, 0);
            acc[1][0] = __builtin_amdgcn_mfma_f32_16x16x32_bf16(a1, b0, acc[1][0], 0, 0, 0);
            acc[1][1] = __builtin_amdgcn_mfma_f32_16x16x32_bf16(a1, b1, acc[1][1], 0, 0, 0);
            acc[1][2] = __builtin_amdgcn_mfma_f32_16x16x32_bf16(a1, b2, acc[1][2], 0, 0, 0);
            acc[1][3] = __builtin_amdgcn_mfma_f32_16x16x32_bf16(a1, b3, acc[1][3], 0, 0, 0);
        }
    }
    // ---- C-write: D col = lane&15 (o), row = (lane>>4)*4+reg (pixel) ----
    float* op = outpre + (b * 256 + wv * 64) * HW + h * 64 + half * 32;
#pragma unroll
    for (int mi = 0; mi < 2; ++mi)
#pragma unroll
        for (int ni = 0; ni < 4; ++ni)
#pragma unroll
            for (int r = 0; r < 4; ++r) {
                int o = ni * 16 + (l & 15);
                int m = mi * 16 + (l >> 4) * 4 + r;
                unsafeAtomicAdd(op + o * HW + m, acc[mi][ni][r]);
            }
}

__global__ __launch_bounds__(1024) void k_stats(const float* __restrict__ outpre,
                                                const float* __restrict__ gamma,
                                                const float* __restrict__ beta,
                                                float* __restrict__ bn) {
    int o = blockIdx.x;
    int tid = threadIdx.x;
    float s = 0.f, sq = 0.f;
    for (int f = tid; f < 16384; f += 1024) {
        int bb = f >> 12, hw = f & 4095;
        float v = outpre[((bb * 256 + o) << 12) + hw];
        s += v;
        sq += v * v;
    }
    __shared__ float rs[1024], rq[1024];
    rs[tid] = s; rq[tid] = sq;
    __syncthreads();
    for (int st = 512; st > 0; st >>= 1) {
        if (tid < st) { rs[tid] += rs[tid + st]; rq[tid] += rq[tid + st]; }
        __syncthreads();
    }
    if (tid == 0) {
        float mu = rs[0] * (1.f / 16384.f);
        float var = rq[0] * (1.f / 16384.f) - mu * mu;
        float sc = gamma[o] / sqrtf(var + 1e-5f);
        bn[o] = sc;
        bn[256 + o] = beta[o] - mu * sc;
    }
}

__global__ __launch_bounds__(256) void k_apply(const float* __restrict__ outpre,
                                               const float* __restrict__ bn,
                                               float* __restrict__ out) {
    int i4 = blockIdx.x * 256 + threadIdx.x;   // 1048576 float4s
    int o = (i4 >> 10) & 255;
    float sc = bn[o], sh = bn[256 + o];
    float4 v = ((const float4*)outpre)[i4];
    v.x = fmaxf(fmaf(v.x, sc, sh), 0.f);
    v.y = fmaxf(fmaf(v.y, sc, sh), 0.f);
    v.z = fmaxf(fmaf(v.z, sc, sh), 0.f);
    v.w = fmaxf(fmaf(v.w, sc, sh), 0.f);
    ((float4*)out)[i4] = v;
}

extern "C" void kernel_launch(void* const* d_in, const int* in_sizes, int n_in,
                              void* d_out, int out_size, void* d_ws, size_t ws_size,
                              hipStream_t stream) {
    const float* x      = (const float*)d_in[0];
    const float* w_off  = (const float*)d_in[1];
    const float* b_off  = (const float*)d_in[2];
    const float* w_conv = (const float*)d_in[3];
    const float* gamma  = (const float*)d_in[4];
    const float* beta   = (const float*)d_in[5];
    float* ws = (float*)d_ws;
    float* off_buf = ws;
    ushort* wtb    = (ushort*)(ws + WS_WT);
    float* outpre  = ws + WS_PRE;
    float* bn      = ws + WS_BN;
    float* out = (float*)d_out;

    hipLaunchKernelGGL(k_wtb,     dim3(256),  dim3(256), 0, stream, w_conv, wtb);
    hipLaunchKernelGGL(k_zero,    dim3(4096), dim3(256), 0, stream, outpre);
    hipLaunchKernelGGL(k_offinit, dim3(1152), dim3(256), 0, stream, b_off, off_buf);
    hipLaunchKernelGGL(k_offconv, dim3(1024), dim3(256), 0, stream, x, w_off, off_buf);
    hipLaunchKernelGGL(k_main,    dim3(2048), dim3(256), 0, stream, x, off_buf, wtb, outpre);
    hipLaunchKernelGGL(k_stats,   dim3(256),  dim3(1024), 0, stream, outpre, gamma, beta, bn);
    hipLaunchKernelGGL(k_apply,   dim3(4096), dim3(256), 0, stream, outpre, bn, out);
}

// Round 7
// 301.698 us; speedup vs baseline: 4.1798x; 1.8517x over previous
//
#include <hip/hip_runtime.h>
#include <hip/hip_bf16.h>

#define HW    4096
#define CIN   256
#define COUT  256
#define NOFF  294912   // 16384*18

// ws layout (float offsets):
// off_buf [294912]            @ 0
// wtb     bf16[2304][256]     @ 294912   (= 294912 float slots)
// outpre  [4][256][4096]      @ 589824   (off_part[4][294912] ALIASES this region,
//                                         consumed by k_offsum before k_main writes)
// bn      [512]               @ 4784128
#define WS_WTB  294912
#define WS_PRE  589824
#define WS_BN   4784128

typedef __attribute__((ext_vector_type(8))) short bf16x8;
typedef __attribute__((ext_vector_type(4))) float f32x4;

__device__ inline ushort f2b(float v) {
    __hip_bfloat16 h = __float2bfloat16(v);
    return *reinterpret_cast<ushort*>(&h);
}

// pack w_conv[o][c][tap] (f32) -> wtb[k>>3][o][k&7] (bf16), k = c*9+tap
__global__ __launch_bounds__(256) void k_wtb(const float* __restrict__ wc,
                                             ushort* __restrict__ wtb) {
    int n = blockIdx.x;
#pragma unroll
    for (int i = 0; i < 9; ++i) {
        int k = i * 256 + threadIdx.x;
        float v = wc[n * 2304 + k];
        wtb[(k >> 3) * 2048 + n * 8 + (k & 7)] = f2b(v);
    }
}

// 4-way channel split, NO atomics: each split writes its own partial buffer.
// blk = bh*4 + s ; channels [s*64, s*64+64), processed 4 per stage.
__global__ __launch_bounds__(256) void k_offconv(const float* __restrict__ x,
                                                 const float* __restrict__ w_off,
                                                 float* __restrict__ off_part) {
    __shared__ float rows[2][4][3][66];
    int blk = blockIdx.x;
    int bh = blk >> 2;
    int s  = blk & 3;
    int b = bh >> 6, h = bh & 63;
    int tid = threadIdx.x;
    int w = tid & 63, cg = tid >> 6;

    // zero halo columns once (never rewritten)
    if (tid < 48) {
        int buf = tid / 24, rem = tid % 24;
        int cl = rem / 6, r = (rem % 6) >> 1, side = rem & 1;
        rows[buf][cl][r][side * 65] = 0.f;
    }
    float acc[5] = {0.f, 0.f, 0.f, 0.f, 0.f};
    const float* xb = x + b * (CIN * HW);
    int cb0 = s * 64;

    // stage it=0 into buf 0: 4 channels x 3 rows x 64
    {
        int cl = tid >> 6, wl = tid & 63;
#pragma unroll
        for (int j = 0; j < 3; ++j) {
            int y = h + j - 1;
            rows[0][cl][j][wl + 1] = (y >= 0 && y < 64) ? xb[(cb0 + cl) * HW + y * 64 + wl] : 0.f;
        }
    }
    __syncthreads();

    for (int it = 0; it < 16; ++it) {
        int cur = it & 1;
        if (it + 1 < 16) {                       // prefetch next 4 channels
            int cl = tid >> 6, wl = tid & 63;
            int cnext = cb0 + (it + 1) * 4 + cl;
#pragma unroll
            for (int j = 0; j < 3; ++j) {
                int y = h + j - 1;
                rows[cur ^ 1][cl][j][wl + 1] = (y >= 0 && y < 64) ? xb[cnext * HW + y * 64 + wl] : 0.f;
            }
        }
#pragma unroll
        for (int cl = 0; cl < 4; ++cl) {
            int c = cb0 + it * 4 + cl;
            float v[9];
#pragma unroll
            for (int dy = 0; dy < 3; ++dy)
#pragma unroll
                for (int dx = 0; dx < 3; ++dx)
                    v[dy * 3 + dx] = rows[cur][cl][dy][w + dx];
#pragma unroll
            for (int m = 0; m < 5; ++m) {
                int ch = cg + 4 * m;
                if (ch < 18) {
                    const float* wp = w_off + __builtin_amdgcn_readfirstlane(ch * (CIN * 9) + c * 9);
#pragma unroll
                    for (int tq = 0; tq < 9; ++tq) acc[m] += wp[tq] * v[tq];
                }
            }
        }
        __syncthreads();
    }
    int pix = bh * 64 + w;
    float* op = off_part + s * NOFF;
#pragma unroll
    for (int m = 0; m < 5; ++m) {
        int ch = cg + 4 * m;
        if (ch < 18) op[pix * 18 + ch] = acc[m];
    }
}

// off_buf = bias + sum of 4 partials
__global__ __launch_bounds__(256) void k_offsum(const float* __restrict__ off_part,
                                                const float* __restrict__ b_off,
                                                float* __restrict__ off_buf) {
    int i = blockIdx.x * 256 + threadIdx.x;      // < 294912
    float v = b_off[i % 18];
    v += off_part[i] + off_part[NOFF + i] + off_part[2 * NOFF + i] + off_part[3 * NOFF + i];
    off_buf[i] = v;
}

#define PAD_K 296   // 288 + 8 bf16 pad

// grid 1024: mt = b*256 + h*4 + quarter (16-pixel M-tile), full K in-block, direct stores.
// MFMA operand roles: A = weights (rows=o), B = samples (cols=px) -> D[o][px], coalesced stores.
// Each wave owns o in [wv*64, wv*64+64): acc[4] frags of 16 rows.
__global__ __launch_bounds__(256, 4) void k_main(const float* __restrict__ x,
                                                 const float* __restrict__ off_buf,
                                                 const ushort* __restrict__ wtb,
                                                 float* __restrict__ outpre) {
    __shared__ ushort A_lds[16 * PAD_K];     // 9472 B: samples, row=px, k = cloc*9+tap
    __shared__ uint2  m_idx[144];            // [tap*16+px]: packed corner indices
    __shared__ float4 m_w[144];              // [tap*16+px]: bilinear weights (masked)
    int mt = blockIdx.x;
    int b       = mt >> 8;
    int h       = (mt >> 2) & 63;
    int quarter = mt & 3;
    int tid = threadIdx.x;
    int l  = tid & 63;
    int wv = tid >> 6;                 // wave -> o base = wv*64
    int px  = tid & 15;                // gather pixel within tile
    int grp = tid >> 4;                // 16 groups x 2 channels

    const float* xb = x + b * (CIN * HW);

    // ---- prologue: bilinear metadata once per (px, tap) ----
    if (tid < 144) {
        int ppx = tid & 15, tap = tid >> 4;
        int imgc = quarter * 16 + ppx;
        int pg = (b * 64 + h) * 64 + imgc;
        float offy = off_buf[pg * 18 + 2 * tap];
        float offx = off_buf[pg * 18 + 2 * tap + 1];
        float py  = (float)(h + tap / 3 - 1) + offy;
        float pxf = (float)(imgc + tap % 3 - 1) + offx;
        float fy0 = floorf(py), fx0 = floorf(pxf);
        int y0 = (int)fy0, x0 = (int)fx0;
        float fy = py - fy0, fx = pxf - fx0;
        float wy0 = (1.f - fy) * ((y0 >= 0 && y0 < 64) ? 1.f : 0.f);
        float wy1 = fy         * ((y0 >= -1 && y0 < 63) ? 1.f : 0.f);
        float wx0 = (1.f - fx) * ((x0 >= 0 && x0 < 64) ? 1.f : 0.f);
        float wx1 = fx         * ((x0 >= -1 && x0 < 63) ? 1.f : 0.f);
        int iy0 = min(max(y0, 0), 63) * 64;
        int iy1 = min(max(y0 + 1, 0), 63) * 64;
        int ix0 = min(max(x0, 0), 63);
        int ix1 = min(max(x0 + 1, 0), 63);
        m_idx[tid] = (uint2){ (uint)((iy0 + ix0) | ((iy0 + ix1) << 16)),
                              (uint)((iy1 + ix0) | ((iy1 + ix1) << 16)) };
        m_w[tid] = (float4){ wy0 * wx0, wy0 * wx1, wy1 * wx0, wy1 * wx1 };
    }

    f32x4 acc[4];
#pragma unroll
    for (int f = 0; f < 4; ++f) acc[f] = (f32x4){0.f, 0.f, 0.f, 0.f};

    for (int chunk = 0; chunk < 8; ++chunk) {
        int c0 = chunk * 32;
        __syncthreads();               // A_lds reuse guard (+ meta ready on chunk 0)
        // ---- gather: 16 px x 32 ch x 9 taps -> bf16 LDS ----
#pragma unroll
        for (int tap = 0; tap < 9; ++tap) {
            int t = tap * 16 + px;
            uint2 id = m_idx[t];
            float4 w4 = m_w[t];
            int i00 = id.x & 0xffff, i01 = id.x >> 16;
            int i10 = id.y & 0xffff, i11 = id.y >> 16;
#pragma unroll
            for (int cl = 0; cl < 2; ++cl) {
                int cloc = grp * 2 + cl;
                const float* pl = xb + (c0 + cloc) * HW;
                float v = w4.x * pl[i00] + w4.y * pl[i01] +
                          w4.z * pl[i10] + w4.w * pl[i11];
                A_lds[px * PAD_K + cloc * 9 + tap] = f2b(v);
            }
        }
        __syncthreads();
        // ---- MFMA: K-chunk = 288 = 9 steps of 32 ----
        int kg0 = chunk * 288;
        for (int st = 0; st < 9; ++st) {
            int kb = st * 32;
            int koff = kb + (l >> 4) * 8;
            bf16x8 smp = *(const bf16x8*)&A_lds[(l & 15) * PAD_K + koff];
            int ko = ((kg0 + kb) >> 3) + (l >> 4);
            const ushort* ap = wtb + ko * 2048 + (wv * 64 + (l & 15)) * 8;
            bf16x8 w0 = *(const bf16x8*)(ap);
            bf16x8 w1 = *(const bf16x8*)(ap + 128);
            bf16x8 w2 = *(const bf16x8*)(ap + 256);
            bf16x8 w3 = *(const bf16x8*)(ap + 384);
            acc[0] = __builtin_amdgcn_mfma_f32_16x16x32_bf16(w0, smp, acc[0], 0, 0, 0);
            acc[1] = __builtin_amdgcn_mfma_f32_16x16x32_bf16(w1, smp, acc[1], 0, 0, 0);
            acc[2] = __builtin_amdgcn_mfma_f32_16x16x32_bf16(w2, smp, acc[2], 0, 0, 0);
            acc[3] = __builtin_amdgcn_mfma_f32_16x16x32_bf16(w3, smp, acc[3], 0, 0, 0);
        }
    }
    // ---- direct store: D row=(l>>4)*4+r -> o (within 16-frag), col=l&15 -> px ----
    float* op = outpre + (size_t)(b * 256) * HW + h * 64 + quarter * 16;
#pragma unroll
    for (int f = 0; f < 4; ++f)
#pragma unroll
        for (int r = 0; r < 4; ++r) {
            int o = wv * 64 + f * 16 + (l >> 4) * 4 + r;
            op[o * HW + (l & 15)] = acc[f][r];
        }
}

__global__ __launch_bounds__(1024) void k_stats(const float* __restrict__ outpre,
                                                const float* __restrict__ gamma,
                                                const float* __restrict__ beta,
                                                float* __restrict__ bn) {
    int o = blockIdx.x;
    int tid = threadIdx.x;
    float s = 0.f, sq = 0.f;
    for (int f = tid; f < 16384; f += 1024) {
        int bb = f >> 12, hw = f & 4095;
        float v = outpre[((bb * 256 + o) << 12) + hw];
        s += v;
        sq += v * v;
    }
    __shared__ float rs[1024], rq[1024];
    rs[tid] = s; rq[tid] = sq;
    __syncthreads();
    for (int st = 512; st > 0; st >>= 1) {
        if (tid < st) { rs[tid] += rs[tid + st]; rq[tid] += rq[tid + st]; }
        __syncthreads();
    }
    if (tid == 0) {
        float mu = rs[0] * (1.f / 16384.f);
        float var = rq[0] * (1.f / 16384.f) - mu * mu;
        float sc = gamma[o] / sqrtf(var + 1e-5f);
        bn[o] = sc;
        bn[256 + o] = beta[o] - mu * sc;
    }
}

__global__ __launch_bounds__(256) void k_apply(const float* __restrict__ outpre,
                                               const float* __restrict__ bn,
                                               float* __restrict__ out) {
    int i4 = blockIdx.x * 256 + threadIdx.x;   // 1048576 float4s
    int o = (i4 >> 10) & 255;
    float sc = bn[o], sh = bn[256 + o];
    float4 v = ((const float4*)outpre)[i4];
    v.x = fmaxf(fmaf(v.x, sc, sh), 0.f);
    v.y = fmaxf(fmaf(v.y, sc, sh), 0.f);
    v.z = fmaxf(fmaf(v.z, sc, sh), 0.f);
    v.w = fmaxf(fmaf(v.w, sc, sh), 0.f);
    ((float4*)out)[i4] = v;
}

extern "C" void kernel_launch(void* const* d_in, const int* in_sizes, int n_in,
                              void* d_out, int out_size, void* d_ws, size_t ws_size,
                              hipStream_t stream) {
    const float* x      = (const float*)d_in[0];
    const float* w_off  = (const float*)d_in[1];
    const float* b_off  = (const float*)d_in[2];
    const float* w_conv = (const float*)d_in[3];
    const float* gamma  = (const float*)d_in[4];
    const float* beta   = (const float*)d_in[5];
    float* ws = (float*)d_ws;
    float* off_buf  = ws;
    ushort* wtb     = (ushort*)(ws + WS_WTB);
    float* outpre   = ws + WS_PRE;
    float* off_part = outpre;               // alias: consumed before k_main writes
    float* bn       = ws + WS_BN;
    float* out = (float*)d_out;

    hipLaunchKernelGGL(k_wtb,     dim3(256),  dim3(256), 0, stream, w_conv, wtb);
    hipLaunchKernelGGL(k_offconv, dim3(1024), dim3(256), 0, stream, x, w_off, off_part);
    hipLaunchKernelGGL(k_offsum,  dim3(1152), dim3(256), 0, stream, off_part, b_off, off_buf);
    hipLaunchKernelGGL(k_main,    dim3(1024), dim3(256), 0, stream, x, off_buf, wtb, outpre);
    hipLaunchKernelGGL(k_stats,   dim3(256),  dim3(1024), 0, stream, outpre, gamma, beta, bn);
    hipLaunchKernelGGL(k_apply,   dim3(4096), dim3(256), 0, stream, outpre, bn, out);
}

// Round 8
// 244.126 us; speedup vs baseline: 5.1656x; 1.2358x over previous
//
#include <hip/hip_runtime.h>
#include <hip/hip_bf16.h>

#define HW    4096
#define CIN   256
#define COUT  256
#define NOFF  294912   // 16384*18

// ws layout (float offsets):
// off_buf [294912]            @ 0
// wtb     bf16[2304][256]     @ 294912   (= 294912 float slots)
// outpre  [4][256][4096]      @ 589824   (off_part[4][294912] ALIASES this region,
//                                         consumed by k_offsum before k_main writes)
// bn      [512]               @ 4784128
// xt (NHWC f32 [4][4096][256]) lives in d_out (16.8 MB), consumed by k_main
// before k_apply overwrites d_out with the final result.
#define WS_WTB  294912
#define WS_PRE  589824
#define WS_BN   4784128

typedef __attribute__((ext_vector_type(8))) short bf16x8;
typedef __attribute__((ext_vector_type(4))) float f32x4;

__device__ inline ushort f2b(float v) {
    __hip_bfloat16 h = __float2bfloat16(v);
    return *reinterpret_cast<ushort*>(&h);
}

// pack w_conv[o][c][tap] (f32) -> wtb[k>>3][o][k&7] (bf16), k = c*9+tap
__global__ __launch_bounds__(256) void k_wtb(const float* __restrict__ wc,
                                             ushort* __restrict__ wtb) {
    int n = blockIdx.x;
#pragma unroll
    for (int i = 0; i < 9; ++i) {
        int k = i * 256 + threadIdx.x;
        float v = wc[n * 2304 + k];
        wtb[(k >> 3) * 2048 + n * 8 + (k & 7)] = f2b(v);
    }
}

// NCHW -> NHWC transpose: xt[b][hw][c] = x[b][c][hw]
// grid = b(4) x ct(4) x hwt(64); block 256. LDS 64x65 tile (conflict-free both ways).
__global__ __launch_bounds__(256) void k_xt(const float* __restrict__ x,
                                            float* __restrict__ xt) {
    __shared__ float tile[64][65];
    int blk = blockIdx.x;
    int b   = blk >> 8;
    int ct  = (blk >> 6) & 3;
    int hwt = blk & 63;
    int tid = threadIdx.x;
    const float* xb = x + ((size_t)(b * 256 + ct * 64)) * HW + hwt * 64;
#pragma unroll
    for (int p = 0; p < 16; ++p) {
        int c_l = p * 4 + (tid >> 6);
        int hw_l = tid & 63;
        tile[c_l][hw_l] = xb[(size_t)c_l * HW + hw_l];
    }
    __syncthreads();
    float* xo = xt + ((size_t)b * HW + hwt * 64) * 256 + ct * 64;
#pragma unroll
    for (int p = 0; p < 16; ++p) {
        int hw_l = p * 4 + (tid >> 6);
        int c_l = tid & 63;
        xo[(size_t)hw_l * 256 + c_l] = tile[c_l][hw_l];
    }
}

// 4-way channel split, NO atomics: each split writes its own partial buffer.
__global__ __launch_bounds__(256) void k_offconv(const float* __restrict__ x,
                                                 const float* __restrict__ w_off,
                                                 float* __restrict__ off_part) {
    __shared__ float rows[2][4][3][66];
    int blk = blockIdx.x;
    int bh = blk >> 2;
    int s  = blk & 3;
    int b = bh >> 6, h = bh & 63;
    int tid = threadIdx.x;
    int w = tid & 63, cg = tid >> 6;

    if (tid < 48) {
        int buf = tid / 24, rem = tid % 24;
        int cl = rem / 6, r = (rem % 6) >> 1, side = rem & 1;
        rows[buf][cl][r][side * 65] = 0.f;
    }
    float acc[5] = {0.f, 0.f, 0.f, 0.f, 0.f};
    const float* xb = x + b * (CIN * HW);
    int cb0 = s * 64;

    {
        int cl = tid >> 6, wl = tid & 63;
#pragma unroll
        for (int j = 0; j < 3; ++j) {
            int y = h + j - 1;
            rows[0][cl][j][wl + 1] = (y >= 0 && y < 64) ? xb[(cb0 + cl) * HW + y * 64 + wl] : 0.f;
        }
    }
    __syncthreads();

    for (int it = 0; it < 16; ++it) {
        int cur = it & 1;
        if (it + 1 < 16) {
            int cl = tid >> 6, wl = tid & 63;
            int cnext = cb0 + (it + 1) * 4 + cl;
#pragma unroll
            for (int j = 0; j < 3; ++j) {
                int y = h + j - 1;
                rows[cur ^ 1][cl][j][wl + 1] = (y >= 0 && y < 64) ? xb[cnext * HW + y * 64 + wl] : 0.f;
            }
        }
#pragma unroll
        for (int cl = 0; cl < 4; ++cl) {
            int c = cb0 + it * 4 + cl;
            float v[9];
#pragma unroll
            for (int dy = 0; dy < 3; ++dy)
#pragma unroll
                for (int dx = 0; dx < 3; ++dx)
                    v[dy * 3 + dx] = rows[cur][cl][dy][w + dx];
#pragma unroll
            for (int m = 0; m < 5; ++m) {
                int ch = cg + 4 * m;
                if (ch < 18) {
                    const float* wp = w_off + __builtin_amdgcn_readfirstlane(ch * (CIN * 9) + c * 9);
#pragma unroll
                    for (int tq = 0; tq < 9; ++tq) acc[m] += wp[tq] * v[tq];
                }
            }
        }
        __syncthreads();
    }
    int pix = bh * 64 + w;
    float* op = off_part + s * NOFF;
#pragma unroll
    for (int m = 0; m < 5; ++m) {
        int ch = cg + 4 * m;
        if (ch < 18) op[pix * 18 + ch] = acc[m];
    }
}

// off_buf = bias + sum of 4 partials
__global__ __launch_bounds__(256) void k_offsum(const float* __restrict__ off_part,
                                                const float* __restrict__ b_off,
                                                float* __restrict__ off_buf) {
    int i = blockIdx.x * 256 + threadIdx.x;      // < 294912
    float v = b_off[i % 18];
    v += off_part[i] + off_part[NOFF + i] + off_part[2 * NOFF + i] + off_part[3 * NOFF + i];
    off_buf[i] = v;
}

#define PAD_K 296   // 288 + 8 bf16 pad

// grid 1024: mt = b*256 + h*4 + quarter (16-pixel M-tile), full K in-block.
// Gather reads NHWC xt: per (px,tap) pair a 32-lane group loads 32 contiguous
// channels per corner (coalesced 128B segments).
// MFMA: A = weights (rows=o), B = samples (cols=px) -> D[o][px], coalesced stores.
__global__ __launch_bounds__(256, 4) void k_main(const float* __restrict__ xt,
                                                 const float* __restrict__ off_buf,
                                                 const ushort* __restrict__ wtb,
                                                 float* __restrict__ outpre) {
    __shared__ ushort A_lds[16 * PAD_K];     // samples, row=px, k = cloc*9+tap
    __shared__ uint2  m_idx[144];            // [tap*16+px]: packed corner hw-indices
    __shared__ float4 m_w[144];              // [tap*16+px]: bilinear weights (masked)
    int mt = blockIdx.x;
    int b       = mt >> 8;
    int h       = (mt >> 2) & 63;
    int quarter = mt & 3;
    int tid = threadIdx.x;
    int l  = tid & 63;
    int wv = tid >> 6;                 // wave -> o base = wv*64

    // ---- prologue: bilinear metadata once per (px, tap) ----
    if (tid < 144) {
        int ppx = tid & 15, tap = tid >> 4;
        int imgc = quarter * 16 + ppx;
        int pg = (b * 64 + h) * 64 + imgc;
        float offy = off_buf[pg * 18 + 2 * tap];
        float offx = off_buf[pg * 18 + 2 * tap + 1];
        float py  = (float)(h + tap / 3 - 1) + offy;
        float pxf = (float)(imgc + tap % 3 - 1) + offx;
        float fy0 = floorf(py), fx0 = floorf(pxf);
        int y0 = (int)fy0, x0 = (int)fx0;
        float fy = py - fy0, fx = pxf - fx0;
        float wy0 = (1.f - fy) * ((y0 >= 0 && y0 < 64) ? 1.f : 0.f);
        float wy1 = fy         * ((y0 >= -1 && y0 < 63) ? 1.f : 0.f);
        float wx0 = (1.f - fx) * ((x0 >= 0 && x0 < 64) ? 1.f : 0.f);
        float wx1 = fx         * ((x0 >= -1 && x0 < 63) ? 1.f : 0.f);
        int iy0 = min(max(y0, 0), 63) * 64;
        int iy1 = min(max(y0 + 1, 0), 63) * 64;
        int ix0 = min(max(x0, 0), 63);
        int ix1 = min(max(x0 + 1, 0), 63);
        m_idx[tid] = (uint2){ (uint)((iy0 + ix0) | ((iy0 + ix1) << 16)),
                              (uint)((iy1 + ix0) | ((iy1 + ix1) << 16)) };
        m_w[tid] = (float4){ wy0 * wx0, wy0 * wx1, wy1 * wx0, wy1 * wx1 };
    }

    f32x4 acc[4];
#pragma unroll
    for (int f = 0; f < 4; ++f) acc[f] = (f32x4){0.f, 0.f, 0.f, 0.f};

    const float* xtb = xt + (size_t)b * HW * 256;
    int cl = tid & 31;                 // channel lane within chunk
    int p0 = tid >> 5;                 // pair base (0..7)

    for (int chunk = 0; chunk < 8; ++chunk) {
        int c0 = chunk * 32;
        __syncthreads();               // A_lds reuse guard (+ meta ready on chunk 0)
        // ---- gather: 144 (px,tap) pairs x 32 contiguous channels ----
        const float* bp = xtb + c0 + cl;
#pragma unroll
        for (int pp = 0; pp < 18; ++pp) {
            int pair = pp * 8 + p0;
            uint2 id = m_idx[pair];
            float4 w4 = m_w[pair];
            float v = w4.x * bp[(int)(id.x & 0xffffu) << 8]
                    + w4.y * bp[(int)(id.x >> 16) << 8]
                    + w4.z * bp[(int)(id.y & 0xffffu) << 8]
                    + w4.w * bp[(int)(id.y >> 16) << 8];
            int ppx = pair & 15, tap = pair >> 4;
            A_lds[ppx * PAD_K + cl * 9 + tap] = f2b(v);
        }
        __syncthreads();
        // ---- MFMA: K-chunk = 288 = 9 steps of 32 ----
        int kg0 = chunk * 288;
        for (int st = 0; st < 9; ++st) {
            int kb = st * 32;
            int koff = kb + (l >> 4) * 8;
            bf16x8 smp = *(const bf16x8*)&A_lds[(l & 15) * PAD_K + koff];
            int ko = ((kg0 + kb) >> 3) + (l >> 4);
            const ushort* ap = wtb + ko * 2048 + (wv * 64 + (l & 15)) * 8;
            bf16x8 w0 = *(const bf16x8*)(ap);
            bf16x8 w1 = *(const bf16x8*)(ap + 128);
            bf16x8 w2 = *(const bf16x8*)(ap + 256);
            bf16x8 w3 = *(const bf16x8*)(ap + 384);
            acc[0] = __builtin_amdgcn_mfma_f32_16x16x32_bf16(w0, smp, acc[0], 0, 0, 0);
            acc[1] = __builtin_amdgcn_mfma_f32_16x16x32_bf16(w1, smp, acc[1], 0, 0, 0);
            acc[2] = __builtin_amdgcn_mfma_f32_16x16x32_bf16(w2, smp, acc[2], 0, 0, 0);
            acc[3] = __builtin_amdgcn_mfma_f32_16x16x32_bf16(w3, smp, acc[3], 0, 0, 0);
        }
    }
    // ---- direct store: D row=(l>>4)*4+r -> o (within 16-frag), col=l&15 -> px ----
    float* op = outpre + (size_t)(b * 256) * HW + h * 64 + quarter * 16;
#pragma unroll
    for (int f = 0; f < 4; ++f)
#pragma unroll
        for (int r = 0; r < 4; ++r) {
            int o = wv * 64 + f * 16 + (l >> 4) * 4 + r;
            op[o * HW + (l & 15)] = acc[f][r];
        }
}

__global__ __launch_bounds__(1024) void k_stats(const float* __restrict__ outpre,
                                                const float* __restrict__ gamma,
                                                const float* __restrict__ beta,
                                                float* __restrict__ bn) {
    int o = blockIdx.x;
    int tid = threadIdx.x;
    float s = 0.f, sq = 0.f;
    for (int f = tid; f < 16384; f += 1024) {
        int bb = f >> 12, hw = f & 4095;
        float v = outpre[((bb * 256 + o) << 12) + hw];
        s += v;
        sq += v * v;
    }
    __shared__ float rs[1024], rq[1024];
    rs[tid] = s; rq[tid] = sq;
    __syncthreads();
    for (int st = 512; st > 0; st >>= 1) {
        if (tid < st) { rs[tid] += rs[tid + st]; rq[tid] += rq[tid + st]; }
        __syncthreads();
    }
    if (tid == 0) {
        float mu = rs[0] * (1.f / 16384.f);
        float var = rq[0] * (1.f / 16384.f) - mu * mu;
        float sc = gamma[o] / sqrtf(var + 1e-5f);
        bn[o] = sc;
        bn[256 + o] = beta[o] - mu * sc;
    }
}

__global__ __launch_bounds__(256) void k_apply(const float* __restrict__ outpre,
                                               const float* __restrict__ bn,
                                               float* __restrict__ out) {
    int i4 = blockIdx.x * 256 + threadIdx.x;   // 1048576 float4s
    int o = (i4 >> 10) & 255;
    float sc = bn[o], sh = bn[256 + o];
    float4 v = ((const float4*)outpre)[i4];
    v.x = fmaxf(fmaf(v.x, sc, sh), 0.f);
    v.y = fmaxf(fmaf(v.y, sc, sh), 0.f);
    v.z = fmaxf(fmaf(v.z, sc, sh), 0.f);
    v.w = fmaxf(fmaf(v.w, sc, sh), 0.f);
    ((float4*)out)[i4] = v;
}

extern "C" void kernel_launch(void* const* d_in, const int* in_sizes, int n_in,
                              void* d_out, int out_size, void* d_ws, size_t ws_size,
                              hipStream_t stream) {
    const float* x      = (const float*)d_in[0];
    const float* w_off  = (const float*)d_in[1];
    const float* b_off  = (const float*)d_in[2];
    const float* w_conv = (const float*)d_in[3];
    const float* gamma  = (const float*)d_in[4];
    const float* beta   = (const float*)d_in[5];
    float* ws = (float*)d_ws;
    float* off_buf  = ws;
    ushort* wtb     = (ushort*)(ws + WS_WTB);
    float* outpre   = ws + WS_PRE;
    float* off_part = outpre;               // alias: consumed before k_main writes
    float* bn       = ws + WS_BN;
    float* out = (float*)d_out;
    float* xt  = out;                       // d_out doubles as NHWC scratch,
                                            // overwritten by k_apply at the end

    hipLaunchKernelGGL(k_wtb,     dim3(256),  dim3(256), 0, stream, w_conv, wtb);
    hipLaunchKernelGGL(k_xt,      dim3(1024), dim3(256), 0, stream, x, xt);
    hipLaunchKernelGGL(k_offconv, dim3(1024), dim3(256), 0, stream, x, w_off, off_part);
    hipLaunchKernelGGL(k_offsum,  dim3(1152), dim3(256), 0, stream, off_part, b_off, off_buf);
    hipLaunchKernelGGL(k_main,    dim3(1024), dim3(256), 0, stream, xt, off_buf, wtb, outpre);
    hipLaunchKernelGGL(k_stats,   dim3(256),  dim3(1024), 0, stream, outpre, gamma, beta, bn);
    hipLaunchKernelGGL(k_apply,   dim3(4096), dim3(256), 0, stream, outpre, bn, out);
}

// Round 10
// 198.523 us; speedup vs baseline: 6.3522x; 1.2297x over previous
//
#include <hip/hip_runtime.h>
#include <hip/hip_bf16.h>

#define HW    4096
#define CIN   256
#define COUT  256

// ws layout (float offsets):
// off_buf [294912]            @ 0
// wtb     bf16[2304][256]     @ 294912   (294912 float slots)
// outpre  [4][256][4096]      @ 589824   (4194304)
// bn      [512]               @ 4784128
// wob     bf16[288][32][8]    @ 4784640  (36864 float slots)  zero-padded 18->32 rows
// xt (NHWC f32 [4][4096][256]) lives in d_out, consumed before k_apply overwrites it.
#define WS_WTB  294912
#define WS_PRE  589824
#define WS_BN   4784128
#define WS_WOB  4784640

typedef __attribute__((ext_vector_type(8))) short bf16x8;
typedef __attribute__((ext_vector_type(4))) float f32x4;

__device__ inline ushort f2b(float v) {
    __hip_bfloat16 h = __float2bfloat16(v);
    return *reinterpret_cast<ushort*>(&h);
}

// pack w_conv[o][c][tap] (f32) -> wtb[k>>3][o][k&7] (bf16), k = c*9+tap
__global__ __launch_bounds__(256) void k_wtb(const float* __restrict__ wc,
                                             ushort* __restrict__ wtb) {
    int n = blockIdx.x;
#pragma unroll
    for (int i = 0; i < 9; ++i) {
        int k = i * 256 + threadIdx.x;
        float v = wc[n * 2304 + k];
        wtb[(k >> 3) * 2048 + n * 8 + (k & 7)] = f2b(v);
    }
}

// pack w_off[ch][c][tap] -> wob[k>>3][ch32][k&7] (bf16), rows 18..31 zero
__global__ __launch_bounds__(256) void k_wob(const float* __restrict__ w_off,
                                             ushort* __restrict__ wob) {
    int ch = blockIdx.x;                      // 0..31
#pragma unroll
    for (int i = 0; i < 9; ++i) {
        int k = i * 256 + threadIdx.x;
        float v = (ch < 18) ? w_off[ch * 2304 + k] : 0.f;
        wob[(k >> 3) * 256 + ch * 8 + (k & 7)] = f2b(v);
    }
}

// NCHW -> NHWC transpose: xt[b][hw][c] = x[b][c][hw]
__global__ __launch_bounds__(256) void k_xt(const float* __restrict__ x,
                                            float* __restrict__ xt) {
    __shared__ float tile[64][65];
    int blk = blockIdx.x;
    int b   = blk >> 8;
    int ct  = (blk >> 6) & 3;
    int hwt = blk & 63;
    int tid = threadIdx.x;
    const float* xb = x + ((size_t)(b * 256 + ct * 64)) * HW + hwt * 64;
#pragma unroll
    for (int p = 0; p < 16; ++p) {
        int c_l = p * 4 + (tid >> 6);
        int hw_l = tid & 63;
        tile[c_l][hw_l] = xb[(size_t)c_l * HW + hw_l];
    }
    __syncthreads();
    float* xo = xt + ((size_t)b * HW + hwt * 64) * 256 + ct * 64;
#pragma unroll
    for (int p = 0; p < 16; ++p) {
        int hw_l = p * 4 + (tid >> 6);
        int c_l = tid & 63;
        xo[(size_t)hw_l * 256 + c_l] = tile[c_l][hw_l];
    }
}

#define PAD_K 296   // 288 + 8 bf16 pad

// Offset conv as MFMA GEMM: off[18][pix] = W[18][2304] . im2col(x).
// Same skeleton as k_main; taps are integer shifts (mask 0/1), 1 load per pair.
// All 4 waves compute the 2 output frags redundantly; wave 0 stores (+bias).
__global__ __launch_bounds__(256, 4) void k_offmm(const float* __restrict__ xt,
                                                  const ushort* __restrict__ wob,
                                                  const float* __restrict__ b_off,
                                                  float* __restrict__ off_buf) {
    __shared__ ushort A_lds[16 * PAD_K];
    __shared__ int   m2_idx[144];
    __shared__ float m2_w[144];
    int mt = blockIdx.x;
    int b       = mt >> 8;
    int h       = (mt >> 2) & 63;
    int quarter = mt & 3;
    int tid = threadIdx.x;
    int l  = tid & 63;
    int wv = tid >> 6;

    if (tid < 144) {
        int ppx = tid & 15, tap = tid >> 4;
        int imgc = quarter * 16 + ppx;
        int py  = h + tap / 3 - 1;
        int pxx = imgc + tap % 3 - 1;
        bool valid = (py >= 0 && py < 64 && pxx >= 0 && pxx < 64);
        m2_idx[tid] = min(max(py, 0), 63) * 64 + min(max(pxx, 0), 63);
        m2_w[tid] = valid ? 1.f : 0.f;
    }

    f32x4 acc2[2];
    acc2[0] = (f32x4){0.f, 0.f, 0.f, 0.f};
    acc2[1] = (f32x4){0.f, 0.f, 0.f, 0.f};

    const float* xtb = xt + (size_t)b * HW * 256;
    int cl = tid & 31;
    int p0 = tid >> 5;

    for (int chunk = 0; chunk < 8; ++chunk) {
        int c0 = chunk * 32;
        __syncthreads();
        const float* bp = xtb + c0 + cl;
#pragma unroll
        for (int pp = 0; pp < 18; ++pp) {
            int pair = pp * 8 + p0;
            float v = m2_w[pair] * bp[m2_idx[pair] << 8];
            int ppx = pair & 15, tap = pair >> 4;
            A_lds[ppx * PAD_K + cl * 9 + tap] = f2b(v);
        }
        __syncthreads();
        int kg0 = chunk * 288;
        for (int st = 0; st < 9; ++st) {
            int kb = st * 32;
            int koff = kb + (l >> 4) * 8;
            bf16x8 smp = *(const bf16x8*)&A_lds[(l & 15) * PAD_K + koff];
            int ko = ((kg0 + kb) >> 3) + (l >> 4);
            const ushort* ap = wob + ko * 256 + (l & 15) * 8;
            bf16x8 w0 = *(const bf16x8*)(ap);
            bf16x8 w1 = *(const bf16x8*)(ap + 128);
            acc2[0] = __builtin_amdgcn_mfma_f32_16x16x32_bf16(w0, smp, acc2[0], 0, 0, 0);
            acc2[1] = __builtin_amdgcn_mfma_f32_16x16x32_bf16(w1, smp, acc2[1], 0, 0, 0);
        }
    }
    if (wv == 0) {
        int pixbase = (b * 64 + h) * 64 + quarter * 16 + (l & 15);
#pragma unroll
        for (int f = 0; f < 2; ++f)
#pragma unroll
            for (int r = 0; r < 4; ++r) {
                int ch = f * 16 + (l >> 4) * 4 + r;
                if (ch < 18) off_buf[pixbase * 18 + ch] = acc2[f][r] + b_off[ch];
            }
    }
}

// grid 1024: mt = b*256 + h*4 + quarter (16-pixel M-tile), full K in-block.
// Gather reads NHWC xt (coalesced 128B per 32-lane group).
// MFMA: A = weights (rows=o), B = samples (cols=px) -> D[o][px], coalesced stores.
__global__ __launch_bounds__(256, 4) void k_main(const float* __restrict__ xt,
                                                 const float* __restrict__ off_buf,
                                                 const ushort* __restrict__ wtb,
                                                 float* __restrict__ outpre) {
    __shared__ ushort A_lds[16 * PAD_K];
    __shared__ uint2  m_idx[144];
    __shared__ float4 m_w[144];
    int mt = blockIdx.x;
    int b       = mt >> 8;
    int h       = (mt >> 2) & 63;
    int quarter = mt & 3;
    int tid = threadIdx.x;
    int l  = tid & 63;
    int wv = tid >> 6;

    if (tid < 144) {
        int ppx = tid & 15, tap = tid >> 4;
        int imgc = quarter * 16 + ppx;
        int pg = (b * 64 + h) * 64 + imgc;
        float offy = off_buf[pg * 18 + 2 * tap];
        float offx = off_buf[pg * 18 + 2 * tap + 1];
        float py  = (float)(h + tap / 3 - 1) + offy;
        float pxf = (float)(imgc + tap % 3 - 1) + offx;
        float fy0 = floorf(py), fx0 = floorf(pxf);
        int y0 = (int)fy0, x0 = (int)fx0;
        float fy = py - fy0, fx = pxf - fx0;
        float wy0 = (1.f - fy) * ((y0 >= 0 && y0 < 64) ? 1.f : 0.f);
        float wy1 = fy         * ((y0 >= -1 && y0 < 63) ? 1.f : 0.f);
        float wx0 = (1.f - fx) * ((x0 >= 0 && x0 < 64) ? 1.f : 0.f);
        float wx1 = fx         * ((x0 >= -1 && x0 < 63) ? 1.f : 0.f);
        int iy0 = min(max(y0, 0), 63) * 64;
        int iy1 = min(max(y0 + 1, 0), 63) * 64;
        int ix0 = min(max(x0, 0), 63);
        int ix1 = min(max(x0 + 1, 0), 63);
        m_idx[tid] = (uint2){ (uint)((iy0 + ix0) | ((iy0 + ix1) << 16)),
                              (uint)((iy1 + ix0) | ((iy1 + ix1) << 16)) };
        m_w[tid] = (float4){ wy0 * wx0, wy0 * wx1, wy1 * wx0, wy1 * wx1 };
    }

    f32x4 acc[4];
#pragma unroll
    for (int f = 0; f < 4; ++f) acc[f] = (f32x4){0.f, 0.f, 0.f, 0.f};

    const float* xtb = xt + (size_t)b * HW * 256;
    int cl = tid & 31;
    int p0 = tid >> 5;

    for (int chunk = 0; chunk < 8; ++chunk) {
        int c0 = chunk * 32;
        __syncthreads();
        const float* bp = xtb + c0 + cl;
#pragma unroll
        for (int pp = 0; pp < 18; ++pp) {
            int pair = pp * 8 + p0;
            uint2 id = m_idx[pair];
            float4 w4 = m_w[pair];
            float v = w4.x * bp[(int)(id.x & 0xffffu) << 8]
                    + w4.y * bp[(int)(id.x >> 16) << 8]
                    + w4.z * bp[(int)(id.y & 0xffffu) << 8]
                    + w4.w * bp[(int)(id.y >> 16) << 8];
            int ppx = pair & 15, tap = pair >> 4;
            A_lds[ppx * PAD_K + cl * 9 + tap] = f2b(v);
        }
        __syncthreads();
        int kg0 = chunk * 288;
        for (int st = 0; st < 9; ++st) {
            int kb = st * 32;
            int koff = kb + (l >> 4) * 8;
            bf16x8 smp = *(const bf16x8*)&A_lds[(l & 15) * PAD_K + koff];
            int ko = ((kg0 + kb) >> 3) + (l >> 4);
            const ushort* ap = wtb + ko * 2048 + (wv * 64 + (l & 15)) * 8;
            bf16x8 w0 = *(const bf16x8*)(ap);
            bf16x8 w1 = *(const bf16x8*)(ap + 128);
            bf16x8 w2 = *(const bf16x8*)(ap + 256);
            bf16x8 w3 = *(const bf16x8*)(ap + 384);
            acc[0] = __builtin_amdgcn_mfma_f32_16x16x32_bf16(w0, smp, acc[0], 0, 0, 0);
            acc[1] = __builtin_amdgcn_mfma_f32_16x16x32_bf16(w1, smp, acc[1], 0, 0, 0);
            acc[2] = __builtin_amdgcn_mfma_f32_16x16x32_bf16(w2, smp, acc[2], 0, 0, 0);
            acc[3] = __builtin_amdgcn_mfma_f32_16x16x32_bf16(w3, smp, acc[3], 0, 0, 0);
        }
    }
    float* op = outpre + (size_t)(b * 256) * HW + h * 64 + quarter * 16;
#pragma unroll
    for (int f = 0; f < 4; ++f)
#pragma unroll
        for (int r = 0; r < 4; ++r) {
            int o = wv * 64 + f * 16 + (l >> 4) * 4 + r;
            op[o * HW + (l & 15)] = acc[f][r];
        }
}

__global__ __launch_bounds__(1024) void k_stats(const float* __restrict__ outpre,
                                                const float* __restrict__ gamma,
                                                const float* __restrict__ beta,
                                                float* __restrict__ bn) {
    int o = blockIdx.x;
    int tid = threadIdx.x;
    float s = 0.f, sq = 0.f;
    for (int f = tid; f < 16384; f += 1024) {
        int bb = f >> 12, hw = f & 4095;
        float v = outpre[((bb * 256 + o) << 12) + hw];
        s += v;
        sq += v * v;
    }
    __shared__ float rs[1024], rq[1024];
    rs[tid] = s; rq[tid] = sq;
    __syncthreads();
    for (int st = 512; st > 0; st >>= 1) {
        if (tid < st) { rs[tid] += rs[tid + st]; rq[tid] += rq[tid + st]; }
        __syncthreads();
    }
    if (tid == 0) {
        float mu = rs[0] * (1.f / 16384.f);
        float var = rq[0] * (1.f / 16384.f) - mu * mu;
        float sc = gamma[o] / sqrtf(var + 1e-5f);
        bn[o] = sc;
        bn[256 + o] = beta[o] - mu * sc;
    }
}

__global__ __launch_bounds__(256) void k_apply(const float* __restrict__ outpre,
                                               const float* __restrict__ bn,
                                               float* __restrict__ out) {
    int i4 = blockIdx.x * 256 + threadIdx.x;
    int o = (i4 >> 10) & 255;
    float sc = bn[o], sh = bn[256 + o];
    float4 v = ((const float4*)outpre)[i4];
    v.x = fmaxf(fmaf(v.x, sc, sh), 0.f);
    v.y = fmaxf(fmaf(v.y, sc, sh), 0.f);
    v.z = fmaxf(fmaf(v.z, sc, sh), 0.f);
    v.w = fmaxf(fmaf(v.w, sc, sh), 0.f);
    ((float4*)out)[i4] = v;
}

extern "C" void kernel_launch(void* const* d_in, const int* in_sizes, int n_in,
                              void* d_out, int out_size, void* d_ws, size_t ws_size,
                              hipStream_t stream) {
    const float* x      = (const float*)d_in[0];
    const float* w_off  = (const float*)d_in[1];
    const float* b_off  = (const float*)d_in[2];
    const float* w_conv = (const float*)d_in[3];
    const float* gamma  = (const float*)d_in[4];
    const float* beta   = (const float*)d_in[5];
    float* ws = (float*)d_ws;
    float* off_buf  = ws;
    ushort* wtb     = (ushort*)(ws + WS_WTB);
    float* outpre   = ws + WS_PRE;
    float* bn       = ws + WS_BN;
    ushort* wob     = (ushort*)(ws + WS_WOB);
    float* out = (float*)d_out;
    float* xt  = out;                       // d_out doubles as NHWC scratch

    hipLaunchKernelGGL(k_wtb,   dim3(256),  dim3(256), 0, stream, w_conv, wtb);
    hipLaunchKernelGGL(k_wob,   dim3(32),   dim3(256), 0, stream, w_off, wob);
    hipLaunchKernelGGL(k_xt,    dim3(1024), dim3(256), 0, stream, x, xt);
    hipLaunchKernelGGL(k_offmm, dim3(1024), dim3(256), 0, stream, xt, wob, b_off, off_buf);
    hipLaunchKernelGGL(k_main,  dim3(1024), dim3(256), 0, stream, xt, off_buf, wtb, outpre);
    hipLaunchKernelGGL(k_stats, dim3(256),  dim3(1024), 0, stream, outpre, gamma, beta, bn);
    hipLaunchKernelGGL(k_apply, dim3(4096), dim3(256), 0, stream, outpre, bn, out);
}